// Round 17
// baseline (130.442 us; speedup 1.0000x reference)
//
#include <hip/hip_runtime.h>
#include <math.h>

typedef _Float16 f16;
typedef __attribute__((ext_vector_type(2))) _Float16 f16x2;
typedef __attribute__((ext_vector_type(4))) _Float16 f16x4;
typedef __attribute__((ext_vector_type(8))) _Float16 f16x8;
typedef __attribute__((ext_vector_type(4))) float f32x4;

#define NBATCH 8
#define WSA_ELE 36864      // 32*1152 (w_off padded to 32 rows, k-major, frag-swizzled)
#define WSB_ELE 147456     // 128*1152 (w_def, k-major, frag-swizzled)
#define PREP_BLOCKS 720    // (WSA_ELE + WSB_ELE) / 256
// workspace byte offsets
#define OFF_WSB  73728

// dynamic LDS layout (bytes)
#define WIN_OFF    0        // 128 KB: 8-row x-window, pixel-slot XOR-swizzled
#define SCR_OFF    131072   // shared scratch, time-disjoint users:
                            //   phase 0: transpose tile [p][c] pitch 130 (16640 B)
                            //   phase 1-2: s_off (2 x 27 x 65 f32 = 14040 B)
#define SMEM_BYTES 148480   // R13/R16-proven size

// ---------------- prep: weights -> fp16, k-major, MFMA-fragment-swizzled ----------------
__global__ __launch_bounds__(256) void prep_w_kernel(const float* __restrict__ w_off,
                                                     const float* __restrict__ w_def,
                                                     f16* __restrict__ wsA,
                                                     f16* __restrict__ wsB) {
  int i = blockIdx.x * 256 + threadIdx.x;
  if (i < WSA_ELE) {
    int j = i & 7, lane = (i >> 3) & 63, fm = i >> 9;
    int ch = fm >> 1, mt = fm & 1;
    int row = mt * 16 + (lane & 15);
    int kidx = ch * 32 + (lane >> 4) * 8 + j;
    int k = kidx >> 7, cc = kidx & 127;
    float v = (row < 27) ? w_off[row * 1152 + cc * 9 + k] : 0.0f;
    wsA[i] = (f16)v;
  } else {
    int e = i - WSA_ELE;
    int j = e & 7, lane = (e >> 3) & 63, fm = e >> 9;
    int ch = fm >> 3, mt = fm & 7;
    int row = mt * 16 + (lane & 15);
    int kidx = ch * 32 + (lane >> 4) * 8 + j;
    int k = kidx >> 7, cc = kidx & 127;
    wsB[e] = (f16)w_def[row * 1152 + cc * 9 + k];
  }
}

// ---------------- fused DCN: 2-row block + LDS x-window; BARRIER-FREE main loop ----------------
// One 512-thread block per (b, row-pair hp); grid 256 = 1 block/CU, one round.
// R17 change vs R16: phase 3's A fragments come DIRECTLY from global wsB
// (288 KB, L2-resident, identical addresses across waves -> L1 broadcast)
// instead of LDS staging. This deletes ALL 37 main-loop barriers (each was a
// forced vmcnt(0) drain, ~400-500 cy serialized at 1 block/CU). win is
// read-only in phase 3 and acc is private -> no LDS hazard, no barrier needed.
// R3's version of this failed because the scattered gathers ALSO sat in the
// same stream with zero prefetch distance; those are now ds_read_b128.
__global__ __launch_bounds__(512, 1) void fused_dcn_kernel(const float* __restrict__ x,
                                                           const f16* __restrict__ wsA,
                                                           const f16* __restrict__ wsB,
                                                           const float* __restrict__ b_off,
                                                           const float* __restrict__ b_def,
                                                           float* __restrict__ out) {
  extern __shared__ __align__(16) char smem[];
  char*  win      = smem + WIN_OFF;
  f16*   tile     = (f16*)(smem + SCR_OFF);     // phase 0, [p][c] pitch 130
  float* s_offall = (float*)(smem + SCR_OFF);   // phases 1-2

  const int t = threadIdx.x;
  const int b = blockIdx.x & 7;                 // XCD = batch
  const int hp = blockIdx.x >> 3;               // row pair 0..31
  const int lane = t & 63, wid = t >> 6;
  const int row = wid >> 2;                     // 0 or 1
  const int rowy = hp * 2 + row;
  const int q = lane >> 4, li = lane & 15;
  const int px = ((wid & 3) << 4) + li;
  const int y_lo = max(hp * 2 - 3, 0);
  const int y_hi = min(hp * 2 + 4, 63);
  const int nrows = y_hi - y_lo + 1;
  const float* xb = x + ((size_t)b << 19);

  // ---- phase 0: build window from x, one row at a time (tile transpose) ----
  for (int rr = 0; rr < nrows; ++rr) {
    const int y = y_lo + rr;
    // step A: coalesced f32x4 (4 px of one channel) -> 4 scalar f16 writes tile[p][c]
    #pragma unroll
    for (int i2 = 0; i2 < 4; ++i2) {
      int it = i2 * 512 + t;                 // 2048 items = 128 c x 16 quads
      int c = it >> 4, g4 = (it & 15) << 2;
      float4 v = *(const float4*)&xb[c * 4096 + y * 64 + g4];
      tile[(g4    ) * 130 + c] = (f16)v.x;
      tile[(g4 + 1) * 130 + c] = (f16)v.y;
      tile[(g4 + 2) * 130 + c] = (f16)v.z;
      tile[(g4 + 3) * 130 + c] = (f16)v.w;
    }
    __syncthreads();
    // step B: ONE b128 read of 8 consecutive channels -> swizzled win write
    #pragma unroll
    for (int j = 0; j < 2; ++j) {
      int u = j * 512 + t;
      int xx = u >> 4, s = u & 15;
      int qq = s & 3, cc4 = s >> 2;
      uint4 bu = *(const uint4*)&tile[xx * 130 + s * 8];
      int s1 = xx & 3, s2 = (xx >> 2) & 1;
      *(uint4*)(win + (((rr * 64 + xx) << 8) + ((qq ^ s1) << 4) + ((cc4 ^ s2) << 6))) = bu;
    }
    __syncthreads();                         // tile reusable; last iter: win ready
  }

  // ---- phase 1: offset conv for this wave's row (taps from window) ----
  {
    float* so = s_offall + row * (27 * 65);
    f32x4 acc0 = {0.f, 0.f, 0.f, 0.f}, acc1 = {0.f, 0.f, 0.f, 0.f};
    #pragma unroll
    for (int k = 0; k < 9; ++k) {
      const int ky = k / 3, kx = k - ky * 3;
      const int y = rowy + ky - 1;
      const int xx = px + kx - 1;
      const bool valid = ((unsigned)y < 64u) && ((unsigned)xx < 64u);
      const int yc = min(max(y, y_lo), y_hi);
      const int xc = min(max(xx, 0), 63);
      const int base = (((yc - y_lo) * 64 + xc) << 8) + ((q ^ (xc & 3)) << 4) + ((((xc >> 2) & 1)) << 6);
      #pragma unroll
      for (int c4 = 0; c4 < 4; ++c4) {
        union { uint4 u; f16x8 v; } bu;
        bu.u = *(const uint4*)(win + (base ^ (c4 << 6)));
        if (!valid) { bu.u.x = 0u; bu.u.y = 0u; bu.u.z = 0u; bu.u.w = 0u; }
        const int ch = k * 4 + c4;
        f16x8 a0 = *(const f16x8*)&wsA[(ch * 2    ) * 512 + lane * 8];
        f16x8 a1 = *(const f16x8*)&wsA[(ch * 2 + 1) * 512 + lane * 8];
        acc0 = __builtin_amdgcn_mfma_f32_16x16x32_f16(a0, bu.v, acc0, 0, 0, 0);
        acc1 = __builtin_amdgcn_mfma_f32_16x16x32_f16(a1, bu.v, acc1, 0, 0, 0);
      }
    }
    #pragma unroll
    for (int mt = 0; mt < 2; ++mt) {
      f32x4 a = mt ? acc1 : acc0;
      #pragma unroll
      for (int r = 0; r < 4; ++r) {
        int oc = mt * 16 + q * 4 + r;
        if (oc < 27) {
          float v = a[r] + b_off[oc];
          if (oc >= 18) v = 1.0f / (1.0f + __expf(-v));
          so[oc * 65 + px] = v;
        }
      }
    }
  }
  __syncthreads();   // offset rows ready (cross-lane LDS ordering)

  // ---- phase 2: per-lane bilinear tables in REGISTERS (window-slot indices) ----
  unsigned posA[9], posB[9];   // packed (i00|i01<<16), (i10|i11<<16); idx = slot*64+x
  f16x4 wts[9];
  {
    const float* so = s_offall + row * (27 * 65);
    #pragma unroll
    for (int k = 0; k < 9; ++k) {
      const int ky = k / 3, kx = k - ky * 3;
      float oy = so[(2 * k    ) * 65 + px];
      float ox = so[(2 * k + 1) * 65 + px];
      float m  = so[(18 + k   ) * 65 + px];
      float py  = oy + (float)(rowy + ky - 1);
      float pxf = ox + (float)(px + kx - 1);
      float y0f = floorf(py), x0f = floorf(pxf);
      float wy = py - y0f, wx = pxf - x0f;
      int y0 = (int)y0f, x0 = (int)x0f;
      bool y0v = (unsigned)y0 < 64u, y1v = (unsigned)(y0 + 1) < 64u;
      bool x0v = (unsigned)x0 < 64u, x1v = (unsigned)(x0 + 1) < 64u;
      int y0a = min(max(y0, y_lo), y_hi), y1a = min(max(y0 + 1, y_lo), y_hi);
      int x0c = min(max(x0, 0), 63),      x1c = min(max(x0 + 1, 0), 63);
      unsigned i00 = (unsigned)((y0a - y_lo) * 64 + x0c);
      unsigned i01 = (unsigned)((y0a - y_lo) * 64 + x1c);
      unsigned i10 = (unsigned)((y1a - y_lo) * 64 + x0c);
      unsigned i11 = (unsigned)((y1a - y_lo) * 64 + x1c);
      posA[k] = i00 | (i01 << 16);
      posB[k] = i10 | (i11 << 16);
      float w0 = (y0v && x0v) ? (1.f - wy) * (1.f - wx) * m : 0.f;
      float w1 = (y0v && x1v) ? (1.f - wy) * wx         * m : 0.f;
      float w2 = (y1v && x0v) ? wy         * (1.f - wx) * m : 0.f;
      float w3 = (y1v && x1v) ? wy         * wx         * m : 0.f;
      f16x4 wp = {(f16)w0, (f16)w1, (f16)w2, (f16)w3};
      wts[k] = wp;
    }
  }
  // NO barrier: nothing writes LDS after this point (win read-only, no s_a)

  // ---- phase 3: 36 chunks, BARRIER-FREE; A direct from global (L1 broadcast) ----
  f32x4 acc[8];
  #pragma unroll
  for (int mt = 0; mt < 8; ++mt) acc[mt] = (f32x4){0.f, 0.f, 0.f, 0.f};

  #pragma unroll
  for (int k = 0; k < 9; ++k) {
    const unsigned wA = posA[k], wB = posB[k];
    const unsigned i00 = wA & 0xFFFFu, i01 = wA >> 16;
    const unsigned i10 = wB & 0xFFFFu, i11 = wB >> 16;
    const int b00 = (int)((i00 << 8) + (((unsigned)q ^ (i00 & 3)) << 4) + (((i00 >> 2) & 1) << 6));
    const int b01 = (int)((i01 << 8) + (((unsigned)q ^ (i01 & 3)) << 4) + (((i01 >> 2) & 1) << 6));
    const int b10 = (int)((i10 << 8) + (((unsigned)q ^ (i10 & 3)) << 4) + (((i10 >> 2) & 1) << 6));
    const int b11 = (int)((i11 << 8) + (((unsigned)q ^ (i11 & 3)) << 4) + (((i11 >> 2) & 1) << 6));
    const f16x4 wv = wts[k];
    const f16x2 wp0 = {wv.x, wv.x}, wp1 = {wv.y, wv.y};
    const f16x2 wp2 = {wv.z, wv.z}, wp3 = {wv.w, wv.w};
    #pragma unroll
    for (int c4 = 0; c4 < 4; ++c4) {
      const int ch = k * 4 + c4;
      // issue A loads FIRST (L2/L1 latency hides under ds_reads + pack)
      union { uint4 u; f16x8 v; } A[8];
      const f16* ab = wsB + ch * 4096;
      #pragma unroll
      for (int mt = 0; mt < 8; ++mt)
        A[mt].u = *(const uint4*)&ab[mt * 512 + lane * 8];
      const int cx = c4 << 6;
      union { uint4 u; f16x2 h[4]; } d0, d1, d2, d3;
      d0.u = *(const uint4*)(win + (b00 ^ cx));
      d1.u = *(const uint4*)(win + (b01 ^ cx));
      d2.u = *(const uint4*)(win + (b10 ^ cx));
      d3.u = *(const uint4*)(win + (b11 ^ cx));
      union { f16x2 h[4]; f16x8 v; } bf;
      #pragma unroll
      for (int i = 0; i < 4; ++i) {
        f16x2 s = d0.h[i] * wp0;
        s = s + d1.h[i] * wp1;
        s = s + d2.h[i] * wp2;
        s = s + d3.h[i] * wp3;
        bf.h[i] = s;
      }
      #pragma unroll
      for (int mt = 0; mt < 8; ++mt)
        acc[mt] = __builtin_amdgcn_mfma_f32_16x16x32_f16(A[mt].v, bf.v, acc[mt], 0, 0, 0);
    }
  }

  float* o = out + (size_t)b * 128 * 4096 + rowy * 64 + px;
  #pragma unroll
  for (int mt = 0; mt < 8; ++mt) {
    #pragma unroll
    for (int r = 0; r < 4; ++r) {
      int oc = mt * 16 + q * 4 + r;
      o[oc * 4096] = acc[mt][r] + b_def[oc];
    }
  }
}

extern "C" void kernel_launch(void* const* d_in, const int* in_sizes, int n_in,
                              void* d_out, int out_size, void* d_ws, size_t ws_size,
                              hipStream_t stream) {
  const float* x     = (const float*)d_in[0];
  const float* w_off = (const float*)d_in[1];
  const float* b_off = (const float*)d_in[2];
  const float* w_def = (const float*)d_in[3];
  const float* b_def = (const float*)d_in[4];
  float* out = (float*)d_out;

  f16* wsA = (f16*)d_ws;
  f16* wsB = (f16*)((char*)d_ws + OFF_WSB);

  static int smem_opted = 0;
  if (!smem_opted) {
    hipFuncSetAttribute((const void*)fused_dcn_kernel,
                        hipFuncAttributeMaxDynamicSharedMemorySize, SMEM_BYTES);
    smem_opted = 1;
  }

  prep_w_kernel<<<dim3(PREP_BLOCKS), dim3(256), 0, stream>>>(w_off, w_def, wsA, wsB);
  fused_dcn_kernel<<<dim3(NBATCH * 32), dim3(512), SMEM_BYTES, stream>>>(
      x, wsA, wsB, b_off, b_def, out);
}

// Round 18
// 110.009 us; speedup vs baseline: 1.1857x; 1.1857x over previous
//
#include <hip/hip_runtime.h>
#include <math.h>

typedef _Float16 f16;
typedef __attribute__((ext_vector_type(2))) _Float16 f16x2;
typedef __attribute__((ext_vector_type(4))) _Float16 f16x4;
typedef __attribute__((ext_vector_type(8))) _Float16 f16x8;
typedef __attribute__((ext_vector_type(4))) float f32x4;

#define NBATCH 8
#define WSA_ELE 36864      // 32*1152 (w_off padded to 32 rows, k-major, frag-swizzled)
#define WSB_ELE 147456     // 128*1152 (w_def, k-major, frag-swizzled)
#define PREP_BLOCKS 720    // (WSA_ELE + WSB_ELE) / 256
// workspace byte offsets
#define OFF_WSB  73728

// dynamic LDS layout (bytes)
#define WIN_OFF    0        // 128 KB: 8-row x-window, pixel-slot XOR-swizzled
#define SCR_OFF    131072   // 17.4 KB shared scratch, time-disjoint users:
                            //   phase 0: transpose tile [p][c] pitch 130 (16640 B)
                            //   phase 3: A double buffer s_a = 2 x 4096 f16 (16384 B)
                            //   phases 1-2: s_off f16 (2 x 27 x 65 = 7020 B) lives at
                            //     scratch+8192, INSIDE buf1 -- legal: buf1's first
                            //     write (stage A(1), chunk 0) is barrier-separated
                            //     from the last s_off read (end of phase 2).
#define SMEM_BYTES 148480   // R13/R16-proven size

__device__ __forceinline__ void gload_lds16(const f16* gsrc, f16* ldst) {
  // global source is PER-LANE (+lane*8 f16); LDS dest is wave-uniform base,
  // HW adds lane*16 bytes.  (R9 lesson: never drop the lane term on src.)
  __builtin_amdgcn_global_load_lds(
      (const __attribute__((address_space(1))) unsigned int*)gsrc,
      (__attribute__((address_space(3))) unsigned int*)ldst, 16, 0, 0);
}

// ---------------- prep: weights -> fp16, k-major, MFMA-fragment-swizzled ----------------
__global__ __launch_bounds__(256) void prep_w_kernel(const float* __restrict__ w_off,
                                                     const float* __restrict__ w_def,
                                                     f16* __restrict__ wsA,
                                                     f16* __restrict__ wsB) {
  int i = blockIdx.x * 256 + threadIdx.x;
  if (i < WSA_ELE) {
    int j = i & 7, lane = (i >> 3) & 63, fm = i >> 9;
    int ch = fm >> 1, mt = fm & 1;
    int row = mt * 16 + (lane & 15);
    int kidx = ch * 32 + (lane >> 4) * 8 + j;
    int k = kidx >> 7, cc = kidx & 127;
    float v = (row < 27) ? w_off[row * 1152 + cc * 9 + k] : 0.0f;
    wsA[i] = (f16)v;
  } else {
    int e = i - WSA_ELE;
    int j = e & 7, lane = (e >> 3) & 63, fm = e >> 9;
    int ch = fm >> 3, mt = fm & 7;
    int row = mt * 16 + (lane & 15);
    int kidx = ch * 32 + (lane >> 4) * 8 + j;
    int k = kidx >> 7, cc = kidx & 127;
    wsB[e] = (f16)w_def[row * 1152 + cc * 9 + k];
  }
}

// ---------------- fused DCN: 2-row block + LDS x-window (R16 structure + overlaps) ----------------
// One 512-thread block per (b, row-pair hp); grid 256 = 1 block/CU, one round.
// Phase 3 = R16's LDS-dbuf A + per-chunk barrier (measured AT the LDS-throughput
// floor: ~780 cy/chunk vs 768 cy of b128 traffic; R17's global-A was +20us).
// New: A(0) staged right after phase 0 (hides under phases 1-2); s_off in f16
// inside buf1's bytes -> the old stage+barrier pair after phase 2 is deleted.
__global__ __launch_bounds__(512, 1) void fused_dcn_kernel(const float* __restrict__ x,
                                                           const f16* __restrict__ wsA,
                                                           const f16* __restrict__ wsB,
                                                           const float* __restrict__ b_off,
                                                           const float* __restrict__ b_def,
                                                           float* __restrict__ out) {
  extern __shared__ __align__(16) char smem[];
  char* win     = smem + WIN_OFF;
  f16*  tile    = (f16*)(smem + SCR_OFF);            // phase 0, [p][c] pitch 130
  f16*  s_a     = (f16*)(smem + SCR_OFF);            // phase 3, 2 x 4096 f16
  f16*  s_offh  = (f16*)(smem + SCR_OFF + 8192);     // phases 1-2 (inside buf1)

  const int t = threadIdx.x;
  const int b = blockIdx.x & 7;                 // XCD = batch
  const int hp = blockIdx.x >> 3;               // row pair 0..31
  const int lane = t & 63, wid = t >> 6;
  const int row = wid >> 2;                     // 0 or 1
  const int rowy = hp * 2 + row;
  const int q = lane >> 4, li = lane & 15;
  const int px = ((wid & 3) << 4) + li;
  const int y_lo = max(hp * 2 - 3, 0);
  const int y_hi = min(hp * 2 + 4, 63);
  const int nrows = y_hi - y_lo + 1;
  const float* xb = x + ((size_t)b << 19);

  // ---- phase 0: build window from x, one row at a time (tile transpose) ----
  for (int rr = 0; rr < nrows; ++rr) {
    const int y = y_lo + rr;
    // step A: coalesced f32x4 (4 px of one channel) -> 4 scalar f16 writes tile[p][c]
    #pragma unroll
    for (int i2 = 0; i2 < 4; ++i2) {
      int it = i2 * 512 + t;                 // 2048 items = 128 c x 16 quads
      int c = it >> 4, g4 = (it & 15) << 2;
      float4 v = *(const float4*)&xb[c * 4096 + y * 64 + g4];
      tile[(g4    ) * 130 + c] = (f16)v.x;
      tile[(g4 + 1) * 130 + c] = (f16)v.y;
      tile[(g4 + 2) * 130 + c] = (f16)v.z;
      tile[(g4 + 3) * 130 + c] = (f16)v.w;
    }
    __syncthreads();
    // step B: ONE b128 read of 8 consecutive channels -> swizzled win write
    #pragma unroll
    for (int j = 0; j < 2; ++j) {
      int u = j * 512 + t;
      int xx = u >> 4, s = u & 15;
      int qq = s & 3, cc4 = s >> 2;
      uint4 bu = *(const uint4*)&tile[xx * 130 + s * 8];
      int s1 = xx & 3, s2 = (xx >> 2) & 1;
      *(uint4*)(win + (((rr * 64 + xx) << 8) + ((qq ^ s1) << 4) + ((cc4 ^ s2) << 6))) = bu;
    }
    __syncthreads();                         // tile reusable; last iter: win ready + tile dead
  }

  // stage A(0) NOW into buf0 (disjoint from s_offh); latency hides under phases 1-2,
  // drained by the compiler's vmcnt(0) at the phase-1-end barrier.
  gload_lds16(wsB + wid * 512 + lane * 8, s_a + wid * 512);

  // ---- phase 1: offset conv for this wave's row (taps from window) ----
  {
    f16* so = s_offh + row * (27 * 65);
    f32x4 acc0 = {0.f, 0.f, 0.f, 0.f}, acc1 = {0.f, 0.f, 0.f, 0.f};
    #pragma unroll
    for (int k = 0; k < 9; ++k) {
      const int ky = k / 3, kx = k - ky * 3;
      const int y = rowy + ky - 1;
      const int xx = px + kx - 1;
      const bool valid = ((unsigned)y < 64u) && ((unsigned)xx < 64u);
      const int yc = min(max(y, y_lo), y_hi);
      const int xc = min(max(xx, 0), 63);
      const int base = (((yc - y_lo) * 64 + xc) << 8) + ((q ^ (xc & 3)) << 4) + ((((xc >> 2) & 1)) << 6);
      #pragma unroll
      for (int c4 = 0; c4 < 4; ++c4) {
        union { uint4 u; f16x8 v; } bu;
        bu.u = *(const uint4*)(win + (base ^ (c4 << 6)));
        if (!valid) { bu.u.x = 0u; bu.u.y = 0u; bu.u.z = 0u; bu.u.w = 0u; }
        const int ch = k * 4 + c4;
        f16x8 a0 = *(const f16x8*)&wsA[(ch * 2    ) * 512 + lane * 8];
        f16x8 a1 = *(const f16x8*)&wsA[(ch * 2 + 1) * 512 + lane * 8];
        acc0 = __builtin_amdgcn_mfma_f32_16x16x32_f16(a0, bu.v, acc0, 0, 0, 0);
        acc1 = __builtin_amdgcn_mfma_f32_16x16x32_f16(a1, bu.v, acc1, 0, 0, 0);
      }
    }
    #pragma unroll
    for (int mt = 0; mt < 2; ++mt) {
      f32x4 a = mt ? acc1 : acc0;
      #pragma unroll
      for (int r = 0; r < 4; ++r) {
        int oc = mt * 16 + q * 4 + r;
        if (oc < 27) {
          float v = a[r] + b_off[oc];
          if (oc >= 18) v = 1.0f / (1.0f + __expf(-v));
          so[oc * 65 + px] = (f16)v;
        }
      }
    }
  }
  __syncthreads();   // offset rows ready + A(0) staging drained

  // ---- phase 2: per-lane bilinear tables in REGISTERS (window-slot indices) ----
  unsigned posA[9], posB[9];   // packed (i00|i01<<16), (i10|i11<<16); idx = slot*64+x
  f16x4 wts[9];
  {
    const f16* so = s_offh + row * (27 * 65);
    #pragma unroll
    for (int k = 0; k < 9; ++k) {
      const int ky = k / 3, kx = k - ky * 3;
      float oy = (float)so[(2 * k    ) * 65 + px];
      float ox = (float)so[(2 * k + 1) * 65 + px];
      float m  = (float)so[(18 + k   ) * 65 + px];
      float py  = oy + (float)(rowy + ky - 1);
      float pxf = ox + (float)(px + kx - 1);
      float y0f = floorf(py), x0f = floorf(pxf);
      float wy = py - y0f, wx = pxf - x0f;
      int y0 = (int)y0f, x0 = (int)x0f;
      bool y0v = (unsigned)y0 < 64u, y1v = (unsigned)(y0 + 1) < 64u;
      bool x0v = (unsigned)x0 < 64u, x1v = (unsigned)(x0 + 1) < 64u;
      int y0a = min(max(y0, y_lo), y_hi), y1a = min(max(y0 + 1, y_lo), y_hi);
      int x0c = min(max(x0, 0), 63),      x1c = min(max(x0 + 1, 0), 63);
      unsigned i00 = (unsigned)((y0a - y_lo) * 64 + x0c);
      unsigned i01 = (unsigned)((y0a - y_lo) * 64 + x1c);
      unsigned i10 = (unsigned)((y1a - y_lo) * 64 + x0c);
      unsigned i11 = (unsigned)((y1a - y_lo) * 64 + x1c);
      posA[k] = i00 | (i01 << 16);
      posB[k] = i10 | (i11 << 16);
      float w0 = (y0v && x0v) ? (1.f - wy) * (1.f - wx) * m : 0.f;
      float w1 = (y0v && x1v) ? (1.f - wy) * wx         * m : 0.f;
      float w2 = (y1v && x0v) ? wy         * (1.f - wx) * m : 0.f;
      float w3 = (y1v && x1v) ? wy         * wx         * m : 0.f;
      f16x4 wp = {(f16)w0, (f16)w1, (f16)w2, (f16)w3};
      wts[k] = wp;
    }
  }
  __syncthreads();   // all s_off reads done BEFORE buf1 (same bytes) is written

  // ---- phase 3: 36 chunks, corners via ds_read from window, A via LDS dbuf ----
  f32x4 acc[8];
  #pragma unroll
  for (int mt = 0; mt < 8; ++mt) acc[mt] = (f32x4){0.f, 0.f, 0.f, 0.f};

  #pragma unroll
  for (int k = 0; k < 9; ++k) {
    const unsigned wA = posA[k], wB = posB[k];
    const unsigned i00 = wA & 0xFFFFu, i01 = wA >> 16;
    const unsigned i10 = wB & 0xFFFFu, i11 = wB >> 16;
    const int b00 = (int)((i00 << 8) + (((unsigned)q ^ (i00 & 3)) << 4) + (((i00 >> 2) & 1) << 6));
    const int b01 = (int)((i01 << 8) + (((unsigned)q ^ (i01 & 3)) << 4) + (((i01 >> 2) & 1) << 6));
    const int b10 = (int)((i10 << 8) + (((unsigned)q ^ (i10 & 3)) << 4) + (((i10 >> 2) & 1) << 6));
    const int b11 = (int)((i11 << 8) + (((unsigned)q ^ (i11 & 3)) << 4) + (((i11 >> 2) & 1) << 6));
    const f16x4 wv = wts[k];
    const f16x2 wp0 = {wv.x, wv.x}, wp1 = {wv.y, wv.y};
    const f16x2 wp2 = {wv.z, wv.z}, wp3 = {wv.w, wv.w};
    #pragma unroll
    for (int c4 = 0; c4 < 4; ++c4) {
      const int ch = k * 4 + c4;
      if (ch < 35)   // stage A(ch+1) into the other buffer (8 segs by 8 waves)
        gload_lds16(wsB + (ch + 1) * 4096 + wid * 512 + lane * 8,
                    s_a + ((ch + 1) & 1) * 4096 + wid * 512);
      const int cx = c4 << 6;
      union { uint4 u; f16x2 h[4]; } d0, d1, d2, d3;
      d0.u = *(const uint4*)(win + (b00 ^ cx));
      d1.u = *(const uint4*)(win + (b01 ^ cx));
      d2.u = *(const uint4*)(win + (b10 ^ cx));
      d3.u = *(const uint4*)(win + (b11 ^ cx));
      union { f16x2 h[4]; f16x8 v; } bf;
      #pragma unroll
      for (int i = 0; i < 4; ++i) {
        f16x2 s = d0.h[i] * wp0;
        s = s + d1.h[i] * wp1;
        s = s + d2.h[i] * wp2;
        s = s + d3.h[i] * wp3;
        bf.h[i] = s;
      }
      const f16* ab = s_a + (ch & 1) * 4096;
      #pragma unroll
      for (int mt = 0; mt < 8; ++mt) {
        f16x8 a = *(const f16x8*)&ab[mt * 512 + lane * 8];
        acc[mt] = __builtin_amdgcn_mfma_f32_16x16x32_f16(a, bf.v, acc[mt], 0, 0, 0);
      }
      __syncthreads();   // drain A staging + protect dbuf swap
    }
  }

  float* o = out + (size_t)b * 128 * 4096 + rowy * 64 + px;
  #pragma unroll
  for (int mt = 0; mt < 8; ++mt) {
    #pragma unroll
    for (int r = 0; r < 4; ++r) {
      int oc = mt * 16 + q * 4 + r;
      o[oc * 4096] = acc[mt][r] + b_def[oc];
    }
  }
}

extern "C" void kernel_launch(void* const* d_in, const int* in_sizes, int n_in,
                              void* d_out, int out_size, void* d_ws, size_t ws_size,
                              hipStream_t stream) {
  const float* x     = (const float*)d_in[0];
  const float* w_off = (const float*)d_in[1];
  const float* b_off = (const float*)d_in[2];
  const float* w_def = (const float*)d_in[3];
  const float* b_def = (const float*)d_in[4];
  float* out = (float*)d_out;

  f16* wsA = (f16*)d_ws;
  f16* wsB = (f16*)((char*)d_ws + OFF_WSB);

  static int smem_opted = 0;
  if (!smem_opted) {
    hipFuncSetAttribute((const void*)fused_dcn_kernel,
                        hipFuncAttributeMaxDynamicSharedMemorySize, SMEM_BYTES);
    smem_opted = 1;
  }

  prep_w_kernel<<<dim3(PREP_BLOCKS), dim3(256), 0, stream>>>(w_off, w_def, wsA, wsB);
  fused_dcn_kernel<<<dim3(NBATCH * 32), dim3(512), SMEM_BYTES, stream>>>(
      x, wsA, wsB, b_off, b_def, out);
}